// Round 4
// baseline (271.983 us; speedup 1.0000x reference)
//
#include <hip/hip_runtime.h>
#include <math.h>

#define SRATE 32000.0
#define NB 128
#define NT 160000
#define CL 100            // samples per chunk
#define CPB 64            // chunks per tile (one per lane)
#define TPR 25            // tiles per row (NT / (CPB*CL))
#define NTILE 3200        // NB * TPR

#ifndef M_PI
#define M_PI 3.14159265358979323846
#endif

// ws float-index layout:
//   [0,16)    fc: 3 x {b0,b1,b2,a1,a2} stride 5
//   [64,280)  G[k] = Hc^(2^k), k=0..5 (36 floats each)
//   [280,316) H64 = Hc^64
//   [320]     ticket counter (int)
//   [384,3584) flags (int, one per tile)
//   [4096, +19200) Lbuf: per-tile local exit states (6 floats)
#define WS_FC    0
#define WS_G     64
#define WS_H64   280
#define WS_CNT   320
#define WS_FLAGS 384
#define WS_LBUF  4096

// ---------------------------------------------------------------------------
// init: zero flags/counter; f64 coeffs (reference formula); Hc = M^CL and its
// squarings Hc^2..Hc^64. One block, 256 threads.
// State: (y1[n-1],y1[n-2],y2[n-1],y2[n-2],y3[n-1],y3[n-2])
// ---------------------------------------------------------------------------
__global__ __launch_bounds__(256) void eq_init(
    const float* __restrict__ fr, const float* __restrict__ gn,
    const float* __restrict__ qs, float* __restrict__ ws)
{
  __shared__ double dc[24];
  __shared__ double Mb[36], Rb[36], Tb[36];
  const int t = threadIdx.x;
  int* wsi = (int*)ws;
  for (int i = t; i < NTILE; i += 256) wsi[WS_FLAGS + i] = 0;
  if (t == 0) wsi[WS_CNT] = 0;
  if (t == 0) {
    for (int f = 0; f < 3; ++f) {
      double w0 = 2.0 * M_PI * (double)fr[f] / SRATE;
      double A  = exp((double)gn[f] / 40.0 * log(10.0));
      double al = sin(w0) / (2.0 * (double)qs[f]);
      double cw = cos(w0);
      double a0 = 1.0 + al / A;
      double b0 = (1.0 + al*A)/a0, b1 = -2.0*cw/a0, b2 = (1.0 - al*A)/a0;
      double A1 = -2.0*cw/a0,      A2 = (1.0 - al/A)/a0;
      dc[f*8+0]=b0; dc[f*8+1]=b1; dc[f*8+2]=b2; dc[f*8+3]=A1; dc[f*8+4]=A2;
      ws[WS_FC+f*5+0]=(float)b0; ws[WS_FC+f*5+1]=(float)b1; ws[WS_FC+f*5+2]=(float)b2;
      ws[WS_FC+f*5+3]=(float)A1; ws[WS_FC+f*5+4]=(float)A2;
    }
  }
  __syncthreads();
  if (t < 6) {   // one-step homogeneous matrix M, column t
    double s0=0,s1=0,s2=0,s3=0,s4=0,s5=0;
    if (t==0) s0=1; else if (t==1) s1=1; else if (t==2) s2=1;
    else if (t==3) s3=1; else if (t==4) s4=1; else s5=1;
    double y1 = -dc[3]*s0 - dc[4]*s1;
    double y2 = dc[8]*y1 + dc[9]*s0 + dc[10]*s1 - dc[11]*s2 - dc[12]*s3;
    double y3 = dc[16]*y2 + dc[17]*s2 + dc[18]*s3 - dc[19]*s4 - dc[20]*s5;
    Mb[0*6+t]=y1; Mb[1*6+t]=s0; Mb[2*6+t]=y2; Mb[3*6+t]=s2; Mb[4*6+t]=y3; Mb[5*6+t]=s4;
  }
  if (t < 36) Rb[t] = ((t % 7) == 0) ? 1.0 : 0.0;
  __syncthreads();
  const int i = t / 6, j = t % 6;
  int e = CL;                         // Rb = M^CL = Hc
  while (e) {
    if (e & 1) {
      double acc = 0.0;
      if (t < 36) { for (int k = 0; k < 6; ++k) acc += Rb[i*6+k]*Mb[k*6+j]; Tb[t]=acc; }
      __syncthreads();
      if (t < 36) Rb[t] = Tb[t];
      __syncthreads();
    }
    e >>= 1;
    if (e) {
      double acc = 0.0;
      if (t < 36) { for (int k = 0; k < 6; ++k) acc += Mb[i*6+k]*Mb[k*6+j]; Tb[t]=acc; }
      __syncthreads();
      if (t < 36) Mb[t] = Tb[t];
      __syncthreads();
    }
  }
  if (t < 36) ws[WS_G + t] = (float)Rb[t];     // G0 = Hc
  __syncthreads();
  for (int k = 1; k <= 6; ++k) {               // successive squaring
    double acc = 0.0;
    if (t < 36) { for (int m = 0; m < 6; ++m) acc += Rb[i*6+m]*Rb[m*6+j]; Tb[t]=acc; }
    __syncthreads();
    if (t < 36) Rb[t] = Tb[t];
    __syncthreads();
    if (t < 36) {
      if (k <= 5) ws[WS_G + k*36 + t] = (float)Rb[t];   // Hc^(2^k)
      else        ws[WS_H64 + t]      = (float)Rb[t];   // Hc^64
    }
    __syncthreads();
  }
}

// ---------------------------------------------------------------------------
// main: one tile per block (ticketed). Stage tile -> zero-state per-chunk IIR
// -> KS#1 -> publish local exit -> lookback walk for tile entry -> KS#2 ->
// replay with true entries -> write y. x read once, y written once.
// LDS tile: (chunk s, sample j) at lds[s*128 + ((j/4+s)&31)*4 + j%4].
// ---------------------------------------------------------------------------
__global__ __launch_bounds__(64) void eq_main(
    const float* __restrict__ x, float* __restrict__ y,
    const float* __restrict__ cst,      // ws: fc/G/H64 (read-only here)
    int* __restrict__ flags, float* __restrict__ lbuf)
{
  __shared__ float lds[64 * 128];
  __shared__ int s_t;
  const int l = threadIdx.x;
  if (l == 0) s_t = atomicAdd((int*)&((int*)cst)[WS_CNT], 1);
  __syncthreads();
  const int t = s_t;
  const int idx = t % TPR;
  const float* xg = x + (size_t)t * (CPB * CL);

  // stage tile (coalesced: runs of 25 float4 per seg)
  #pragma unroll
  for (int it = 0; it < 25; ++it) {
    int f = it * 64 + l, seg = f / 25, off = f % 25;
    float4 v = *(const float4*)(xg + seg*CL + off*4);
    *(float4*)(&lds[seg*128 + (((off + seg) & 31) << 2)]) = v;
  }
  const float c0=cst[WS_FC+0], c1=cst[WS_FC+1], c2=cst[WS_FC+2], c3=cst[WS_FC+3], c4=cst[WS_FC+4];
  const float c5=cst[WS_FC+5], c6=cst[WS_FC+6], c7=cst[WS_FC+7], c8=cst[WS_FC+8], c9=cst[WS_FC+9];
  const float cA=cst[WS_FC+10],cB=cst[WS_FC+11],cC=cst[WS_FC+12],cD=cst[WS_FC+13],cE=cst[WS_FC+14];
  __syncthreads();

  // x-history at chunk entry (true data, not state)
  float xh1, xh2;
  if (l == 0) {
    if (idx == 0) { xh1 = 0.f; xh2 = 0.f; }
    else { xh1 = xg[-1]; xh2 = xg[-2]; }
  } else {
    const int ps = l - 1;
    xh1 = lds[ps*128 + (((24 + ps) & 31) << 2) + 3];
    xh2 = lds[ps*128 + (((24 + ps) & 31) << 2) + 2];
  }

  // ---- phase A: zero-state IIR over own chunk -> e[6] ----
  float e6[6];
  {
    float x1=xh1, x2=xh2, y1p=0,y1pp=0,y2p=0,y2pp=0,y3p=0,y3pp=0;
    #pragma unroll
    for (int jq = 0; jq < 25; ++jq) {
      float4 xv = *(const float4*)(&lds[l*128 + (((jq + l) & 31) << 2)]);
      #pragma unroll
      for (int q = 0; q < 4; ++q) {
        const float xn = (q==0)?xv.x:(q==1)?xv.y:(q==2)?xv.z:xv.w;
        float y1 = c0*xn + c1*x1  + c2*x2   - c3*y1p - c4*y1pp;
        float y2 = c5*y1 + c6*y1p + c7*y1pp - c8*y2p - c9*y2pp;
        float y3 = cA*y2 + cB*y2p + cC*y2pp - cD*y3p - cE*y3pp;
        x2=x1; x1=xn;
        y1pp=y1p; y1p=y1; y2pp=y2p; y2p=y2; y3pp=y3p; y3p=y3;
      }
    }
    e6[0]=y1p; e6[1]=y1pp; e6[2]=y2p; e6[3]=y2pp; e6[4]=y3p; e6[5]=y3pp;
  }

  // ---- KS#1 (zero tile entry) -> local exit L_t at lane 63 ----
  float v6[6];
  #pragma unroll
  for (int i = 0; i < 6; ++i) v6[i] = e6[i];
  #pragma unroll
  for (int k = 0; k < 6; ++k) {
    const float* G = cst + WS_G + k*36;
    float o[6];
    #pragma unroll
    for (int i = 0; i < 6; ++i) o[i] = __shfl_up(v6[i], 1u << k, 64);
    if (l >= (1 << k)) {
      float nv[6];
      #pragma unroll
      for (int i = 0; i < 6; ++i) {
        float a = v6[i];
        #pragma unroll
        for (int m = 0; m < 6; ++m) a += G[i*6+m]*o[m];
        nv[i] = a;
      }
      #pragma unroll
      for (int i = 0; i < 6; ++i) v6[i] = nv[i];
    }
  }
  // publish local exit (release)
  {
    float Lv = 0.f;
    if (l < 6) Lv = __shfl(v6[l], 63, 64);   // uniform shfl per i? gather below
  }
  float Lg[6];
  #pragma unroll
  for (int i = 0; i < 6; ++i) Lg[i] = __shfl(v6[i], 63, 64);
  if (l < 6) lbuf[(size_t)t*6 + l] = Lg[l];
  __threadfence();
  if (l == 0) __hip_atomic_store(&flags[t], 1, __ATOMIC_RELEASE, __HIP_MEMORY_SCOPE_AGENT);

  // ---- lookback: tile entry sg = X_{t-1} from predecessors' locals ----
  float sg[6] = {0.f,0.f,0.f,0.f,0.f,0.f};
  if (idx > 0) {
    const int rowstart = t - idx;
    if (l < idx) {
      while (__hip_atomic_load(&flags[rowstart + l], __ATOMIC_RELAXED,
                               __HIP_MEMORY_SCOPE_AGENT) == 0)
        __builtin_amdgcn_s_sleep(2);
    }
    __threadfence();   // acquire: predecessors' lbuf now visible
    float Hm[36];
    #pragma unroll
    for (int i = 0; i < 36; ++i) Hm[i] = cst[WS_H64 + i];
    for (int p = rowstart; p < t; ++p) {
      const float* Lp = lbuf + (size_t)p*6;
      float ns[6];
      #pragma unroll
      for (int i = 0; i < 6; ++i) {
        float a = Lp[i];
        #pragma unroll
        for (int m = 0; m < 6; ++m) a += Hm[i*6+m]*sg[m];
        ns[i] = a;
      }
      #pragma unroll
      for (int i = 0; i < 6; ++i) sg[i] = ns[i];
    }
  }

  // ---- adjust lane 0 exit by Hc*sg, KS#2 -> true per-chunk entries ----
  if (l == 0) {
    const float* Hc = cst + WS_G;   // G0
    float ne[6];
    #pragma unroll
    for (int i = 0; i < 6; ++i) {
      float a = e6[i];
      #pragma unroll
      for (int m = 0; m < 6; ++m) a += Hc[i*6+m]*sg[m];
      ne[i] = a;
    }
    #pragma unroll
    for (int i = 0; i < 6; ++i) e6[i] = ne[i];
  }
  #pragma unroll
  for (int i = 0; i < 6; ++i) v6[i] = e6[i];
  #pragma unroll
  for (int k = 0; k < 6; ++k) {
    const float* G = cst + WS_G + k*36;
    float o[6];
    #pragma unroll
    for (int i = 0; i < 6; ++i) o[i] = __shfl_up(v6[i], 1u << k, 64);
    if (l >= (1 << k)) {
      float nv[6];
      #pragma unroll
      for (int i = 0; i < 6; ++i) {
        float a = v6[i];
        #pragma unroll
        for (int m = 0; m < 6; ++m) a += G[i*6+m]*o[m];
        nv[i] = a;
      }
      #pragma unroll
      for (int i = 0; i < 6; ++i) v6[i] = nv[i];
    }
  }
  float en[6];
  #pragma unroll
  for (int i = 0; i < 6; ++i) en[i] = __shfl_up(v6[i], 1, 64);
  if (l == 0) {
    #pragma unroll
    for (int i = 0; i < 6; ++i) en[i] = sg[i];
  }

  // ---- phase C: replay with true entry, write y through LDS ----
  {
    float x1=xh1, x2=xh2;
    float y1p=en[0], y1pp=en[1], y2p=en[2], y2pp=en[3], y3p=en[4], y3pp=en[5];
    #pragma unroll
    for (int jq = 0; jq < 25; ++jq) {
      float4 xv = *(const float4*)(&lds[l*128 + (((jq + l) & 31) << 2)]);
      float4 yv;
      #pragma unroll
      for (int q = 0; q < 4; ++q) {
        const float xn = (q==0)?xv.x:(q==1)?xv.y:(q==2)?xv.z:xv.w;
        float y1 = c0*xn + c1*x1  + c2*x2   - c3*y1p - c4*y1pp;
        float y2 = c5*y1 + c6*y1p + c7*y1pp - c8*y2p - c9*y2pp;
        float y3 = cA*y2 + cB*y2p + cC*y2pp - cD*y3p - cE*y3pp;
        x2=x1; x1=xn;
        y1pp=y1p; y1p=y1; y2pp=y2p; y2p=y2; y3pp=y3p; y3p=y3;
        if (q==0) yv.x=y3; else if (q==1) yv.y=y3; else if (q==2) yv.z=y3; else yv.w=y3;
      }
      *(float4*)(&lds[l*128 + (((jq + l) & 31) << 2)]) = yv;   // own row only
    }
  }
  __syncthreads();
  float* yg = y + (size_t)t * (CPB * CL);
  #pragma unroll
  for (int it = 0; it < 25; ++it) {
    int f = it * 64 + l, seg = f / 25, off = f % 25;
    float4 v = *(const float4*)(&lds[seg*128 + (((off + seg) & 31) << 2)]);
    *(float4*)(yg + seg*CL + off*4) = v;
  }
}

extern "C" void kernel_launch(void* const* d_in, const int* in_sizes, int n_in,
                              void* d_out, int out_size, void* d_ws, size_t ws_size,
                              hipStream_t stream) {
  const float* clip = (const float*)d_in[0];
  const float* fr   = (const float*)d_in[1];
  const float* gn   = (const float*)d_in[2];
  const float* qs   = (const float*)d_in[3];
  float* out = (float*)d_out;
  float* ws  = (float*)d_ws;
  int*   wsi = (int*)d_ws;

  eq_init<<<1, 256, 0, stream>>>(fr, gn, qs, ws);
  eq_main<<<NTILE, 64, 0, stream>>>(clip, out, ws,
                                    wsi + WS_FLAGS, ws + WS_LBUF);
}

// Round 5
// 94.468 us; speedup vs baseline: 2.8791x; 2.8791x over previous
//
#include <hip/hip_runtime.h>
#include <math.h>

#define SRATE 32000.f
#define NB 128            // batch rows
#define NT 160000         // samples per row
#define CL 100            // samples per chunk
#define CPB 64            // chunks per tile (one per lane)
#define TPR 25            // tiles per row
#define NTILE 3200        // NB * TPR
#define NCROW 1600        // chunks per row
#define SEG 25            // chunks per lane in scan

#ifndef M_PI
#define M_PI 3.14159265358979323846
#endif

// f32 coefficients, reference formula (hardware transcendentals).
// c[f*5+{0..4}] = b0,b1,b2,a1,a2 (a0-normalized).
__device__ __forceinline__ void coeffs_f32(
    const float* fr, const float* gn, const float* qs, float* c)
{
  #pragma unroll
  for (int f = 0; f < 3; ++f) {
    float w0 = 2.f * (float)M_PI * fr[f] / SRATE;
    float A  = expf(gn[f] * (2.302585093f / 40.f));   // 10^(g/40)
    float al = sinf(w0) / (2.f * qs[f]);
    float cw = cosf(w0);
    float a0 = 1.f + al / A;
    c[f*5+0] = (1.f + al*A) / a0;
    c[f*5+1] = -2.f * cw / a0;
    c[f*5+2] = (1.f - al*A) / a0;
    c[f*5+3] = -2.f * cw / a0;
    c[f*5+4] = (1.f - al/A) / a0;
  }
}

// LDS tile: 64 chunks x 128-float rows (32 KiB). (chunk s, sample j) at
// lds[s*128 + ((j/4+s)&31)*4 + j%4] — rotation keeps b128 LDS ops at the
// 8-word/bank floor. Tile = 64 consecutive global chunks (contiguous).

// ---------------------------------------------------------------------------
// A: zero-entry-state cascade per chunk -> exit record (8 floats) in
// TRANSPOSED layout eoT[row][plane=c%25][slot=c/25] for coalesced scan reads.
// ---------------------------------------------------------------------------
__global__ __launch_bounds__(64) void eq_a(
    const float* __restrict__ x, const float* __restrict__ fr,
    const float* __restrict__ gn, const float* __restrict__ qs,
    float* __restrict__ eoT)
{
  __shared__ float lds[64 * 128];
  const int l = threadIdx.x;
  const int t = blockIdx.x;
  const int row = t / TPR, g = t % TPR;
  float c[15];
  coeffs_f32(fr, gn, qs, c);
  const float* xg = x + (size_t)t * (CPB * CL);
  #pragma unroll
  for (int it = 0; it < 25; ++it) {          // coalesced 1KB/instr
    int f = it * 64 + l, seg = f / 25, off = f % 25;
    float4 v = *(const float4*)(xg + seg*CL + off*4);
    *(float4*)(&lds[seg*128 + (((off + seg) & 31) << 2)]) = v;
  }
  __syncthreads();
  float x1, x2;
  if (l == 0) {
    if (g == 0) { x1 = 0.f; x2 = 0.f; }
    else { x1 = xg[-1]; x2 = xg[-2]; }
  } else {
    const int ps = l - 1;
    x1 = lds[ps*128 + (((24 + ps) & 31) << 2) + 3];
    x2 = lds[ps*128 + (((24 + ps) & 31) << 2) + 2];
  }
  float y1p=0,y1pp=0,y2p=0,y2pp=0,y3p=0,y3pp=0;
  #pragma unroll
  for (int jq = 0; jq < 25; ++jq) {
    float4 xv = *(const float4*)(&lds[l*128 + (((jq + l) & 31) << 2)]);
    #pragma unroll
    for (int q = 0; q < 4; ++q) {
      const float xn = (q==0)?xv.x:(q==1)?xv.y:(q==2)?xv.z:xv.w;
      float y1 = c[0]*xn + c[1]*x1  + c[2]*x2   - c[3]*y1p  - c[4]*y1pp;
      float y2 = c[5]*y1 + c[6]*y1p + c[7]*y1pp - c[8]*y2p  - c[9]*y2pp;
      float y3 = c[10]*y2 + c[11]*y2p + c[12]*y2pp - c[13]*y3p - c[14]*y3pp;
      x2=x1; x1=xn;
      y1pp=y1p; y1p=y1; y2pp=y2p; y2p=y2; y3pp=y3p; y3p=y3;
    }
  }
  const int ci = g * 64 + l;                 // chunk index within row
  const int plane = ci % 25, slot = ci / 25;
  float* ep = eoT + ((size_t)(row*25 + plane)*64 + slot)*8;
  float4 r0; r0.x=y1p; r0.y=y1pp; r0.z=y2p; r0.w=y2pp;
  float4 r1; r1.x=y3p; r1.y=y3pp; r1.z=0.f; r1.w=0.f;
  *(float4*)ep = r0; *(float4*)(ep+4) = r1;
}

// ---------------------------------------------------------------------------
// B: one block per row. Prologue (f64): Hc = M^CL, G[k] = Hc^(SEG*2^k).
// Then 64-lane Kogge-Stone scan over 1600 chunk-exits; write per-chunk TRUE
// entry states to sgD[row][chunk] (direct layout, coalesced for eq_c).
// ---------------------------------------------------------------------------
__global__ __launch_bounds__(64) void eq_b(
    const float* __restrict__ fr, const float* __restrict__ gn,
    const float* __restrict__ qs, const float* __restrict__ eoT,
    float* __restrict__ sgD)
{
  __shared__ double Mb[36], Rb[36], Tb[36];
  __shared__ float Hs[36], Gs[6*36];
  const int l = threadIdx.x, row = blockIdx.x;
  float c[15];
  coeffs_f32(fr, gn, qs, c);
  // one-step homogeneous matrix M, column l (f64 from f32 coeffs)
  if (l < 6) {
    double s0=0,s1=0,s2=0,s3=0,s4=0,s5=0;
    if (l==0) s0=1; else if (l==1) s1=1; else if (l==2) s2=1;
    else if (l==3) s3=1; else if (l==4) s4=1; else s5=1;
    double y1 = -(double)c[3]*s0 - (double)c[4]*s1;
    double y2 = (double)c[5]*y1 + (double)c[6]*s0 + (double)c[7]*s1
              - (double)c[8]*s2 - (double)c[9]*s3;
    double y3 = (double)c[10]*y2 + (double)c[11]*s2 + (double)c[12]*s3
              - (double)c[13]*s4 - (double)c[14]*s5;
    Mb[0*6+l]=y1; Mb[1*6+l]=s0; Mb[2*6+l]=y2; Mb[3*6+l]=s2; Mb[4*6+l]=y3; Mb[5*6+l]=s4;
  }
  if (l < 36) Rb[l] = ((l % 7) == 0) ? 1.0 : 0.0;
  __syncthreads();
  const int i = l / 6, j = l % 6;
  int e = CL;                                 // Rb = M^CL = Hc
  while (e) {
    if (e & 1) {
      double acc = 0.0;
      if (l < 36) { for (int k = 0; k < 6; ++k) acc += Rb[i*6+k]*Mb[k*6+j]; Tb[l]=acc; }
      __syncthreads();
      if (l < 36) Rb[l] = Tb[l];
      __syncthreads();
    }
    e >>= 1;
    if (e) {
      double acc = 0.0;
      if (l < 36) { for (int k = 0; k < 6; ++k) acc += Mb[i*6+k]*Mb[k*6+j]; Tb[l]=acc; }
      __syncthreads();
      if (l < 36) Mb[l] = Tb[l];
      __syncthreads();
    }
  }
  if (l < 36) { Hs[l] = (float)Rb[l]; Mb[l] = Rb[l]; }
  __syncthreads();
  if (l < 36) Rb[l] = ((l % 7) == 0) ? 1.0 : 0.0;
  __syncthreads();
  e = SEG;                                    // Rb = Hc^SEG
  while (e) {
    if (e & 1) {
      double acc = 0.0;
      if (l < 36) { for (int k = 0; k < 6; ++k) acc += Rb[i*6+k]*Mb[k*6+j]; Tb[l]=acc; }
      __syncthreads();
      if (l < 36) Rb[l] = Tb[l];
      __syncthreads();
    }
    e >>= 1;
    if (e) {
      double acc = 0.0;
      if (l < 36) { for (int k = 0; k < 6; ++k) acc += Mb[i*6+k]*Mb[k*6+j]; Tb[l]=acc; }
      __syncthreads();
      if (l < 36) Mb[l] = Tb[l];
      __syncthreads();
    }
  }
  if (l < 36) Gs[l] = (float)Rb[l];
  __syncthreads();
  for (int k = 1; k < 6; ++k) {               // Gs[k] = Gs[k-1]^2
    double acc = 0.0;
    if (l < 36) { for (int m = 0; m < 6; ++m) acc += Rb[i*6+m]*Rb[m*6+j]; Tb[l]=acc; }
    __syncthreads();
    if (l < 36) Rb[l] = Tb[l];
    __syncthreads();
    if (l < 36) Gs[k*36+l] = (float)Rb[l];
    __syncthreads();
  }

  float H[36];
  #pragma unroll
  for (int q = 0; q < 36; ++q) H[q] = Hs[q];
  const float* rbase = eoT + (size_t)row * (25*64*8);
  // local zero-entry scan over this lane's 25 chunks (coalesced plane reads)
  float u[6] = {0,0,0,0,0,0};
  for (int jj = 0; jj < SEG; ++jj) {
    const float* ep = rbase + (size_t)(jj*64 + l)*8;
    float4 r0 = *(const float4*)ep, r1 = *(const float4*)(ep+4);
    float ev[6] = {r0.x,r0.y,r0.z,r0.w,r1.x,r1.y};
    float nu[6];
    #pragma unroll
    for (int q = 0; q < 6; ++q) {
      float a = ev[q];
      #pragma unroll
      for (int m = 0; m < 6; ++m) a += H[q*6+m]*u[m];
      nu[q] = a;
    }
    #pragma unroll
    for (int q = 0; q < 6; ++q) u[q] = nu[q];
  }
  // Kogge-Stone inclusive scan across lanes
  float v6[6];
  #pragma unroll
  for (int q = 0; q < 6; ++q) v6[q] = u[q];
  #pragma unroll
  for (int k = 0; k < 6; ++k) {
    const float* G = Gs + k*36;
    float o[6];
    #pragma unroll
    for (int q = 0; q < 6; ++q) o[q] = __shfl_up(v6[q], 1u << k, 64);
    if (l >= (1 << k)) {
      float nv[6];
      #pragma unroll
      for (int q = 0; q < 6; ++q) {
        float a = v6[q];
        #pragma unroll
        for (int m = 0; m < 6; ++m) a += G[q*6+m]*o[m];
        nv[q] = a;
      }
      #pragma unroll
      for (int q = 0; q < 6; ++q) v6[q] = nv[q];
    }
  }
  float s[6];
  #pragma unroll
  for (int q = 0; q < 6; ++q) s[q] = __shfl_up(v6[q], 1, 64);
  if (l == 0) {
    #pragma unroll
    for (int q = 0; q < 6; ++q) s[q] = 0.f;
  }
  // replay: write true entry of chunk c = l*SEG + jj, advance s = e + Hc*s
  float* wbase = sgD + (size_t)row * (NCROW*8);
  for (int jj = 0; jj < SEG; ++jj) {
    const float* ep = rbase + (size_t)(jj*64 + l)*8;
    float4 r0 = *(const float4*)(ep), r1 = *(const float4*)(ep+4);
    float ev[6] = {r0.x,r0.y,r0.z,r0.w,r1.x,r1.y};
    float* wp = wbase + (size_t)(l*SEG + jj)*8;
    float4 w0; w0.x=s[0]; w0.y=s[1]; w0.z=s[2]; w0.w=s[3];
    float4 w1; w1.x=s[4]; w1.y=s[5]; w1.z=0.f; w1.w=0.f;
    *(float4*)wp = w0; *(float4*)(wp+4) = w1;
    float ns[6];
    #pragma unroll
    for (int q = 0; q < 6; ++q) {
      float a = ev[q];
      #pragma unroll
      for (int m = 0; m < 6; ++m) a += H[q*6+m]*s[m];
      ns[q] = a;
    }
    #pragma unroll
    for (int q = 0; q < 6; ++q) s[q] = ns[q];
  }
}

// ---------------------------------------------------------------------------
// C: exact cascade per chunk with true entry state (coalesced sgD read);
// writes final output through LDS (coalesced).
// ---------------------------------------------------------------------------
__global__ __launch_bounds__(64) void eq_c(
    const float* __restrict__ x, const float* __restrict__ fr,
    const float* __restrict__ gn, const float* __restrict__ qs,
    const float* __restrict__ sgD, float* __restrict__ y)
{
  __shared__ float lds[64 * 128];
  const int l = threadIdx.x;
  const int t = blockIdx.x;
  const int row = t / TPR, g = t % TPR;
  float c[15];
  coeffs_f32(fr, gn, qs, c);
  const float* xg = x + (size_t)t * (CPB * CL);
  float* yg = y + (size_t)t * (CPB * CL);
  #pragma unroll
  for (int it = 0; it < 25; ++it) {
    int f = it * 64 + l, seg = f / 25, off = f % 25;
    float4 v = *(const float4*)(xg + seg*CL + off*4);
    *(float4*)(&lds[seg*128 + (((off + seg) & 31) << 2)]) = v;
  }
  __syncthreads();
  float x1, x2;
  if (l == 0) {
    if (g == 0) { x1 = 0.f; x2 = 0.f; }
    else { x1 = xg[-1]; x2 = xg[-2]; }
  } else {
    const int ps = l - 1;
    x1 = lds[ps*128 + (((24 + ps) & 31) << 2) + 3];
    x2 = lds[ps*128 + (((24 + ps) & 31) << 2) + 2];
  }
  const float* sp = sgD + ((size_t)row * NCROW + (size_t)(g*64 + l)) * 8;
  float4 s0 = *(const float4*)sp, s1 = *(const float4*)(sp+4);
  float y1p=s0.x, y1pp=s0.y, y2p=s0.z, y2pp=s0.w, y3p=s1.x, y3pp=s1.y;
  #pragma unroll
  for (int jq = 0; jq < 25; ++jq) {
    float4 xv = *(const float4*)(&lds[l*128 + (((jq + l) & 31) << 2)]);
    float4 yv;
    #pragma unroll
    for (int q = 0; q < 4; ++q) {
      const float xn = (q==0)?xv.x:(q==1)?xv.y:(q==2)?xv.z:xv.w;
      float y1 = c[0]*xn + c[1]*x1  + c[2]*x2   - c[3]*y1p  - c[4]*y1pp;
      float y2 = c[5]*y1 + c[6]*y1p + c[7]*y1pp - c[8]*y2p  - c[9]*y2pp;
      float y3 = c[10]*y2 + c[11]*y2p + c[12]*y2pp - c[13]*y3p - c[14]*y3pp;
      x2=x1; x1=xn;
      y1pp=y1p; y1p=y1; y2pp=y2p; y2p=y2; y3pp=y3p; y3p=y3;
      if (q==0) yv.x=y3; else if (q==1) yv.y=y3; else if (q==2) yv.z=y3; else yv.w=y3;
    }
    *(float4*)(&lds[l*128 + (((jq + l) & 31) << 2)]) = yv;   // own row only
  }
  __syncthreads();
  #pragma unroll
  for (int it = 0; it < 25; ++it) {
    int f = it * 64 + l, seg = f / 25, off = f % 25;
    float4 v = *(const float4*)(&lds[seg*128 + (((off + seg) & 31) << 2)]);
    *(float4*)(yg + seg*CL + off*4) = v;
  }
}

// ws: eoT [0, 6.55MB) | sgD [6.55MB, 13.1MB)  (8-float records)
extern "C" void kernel_launch(void* const* d_in, const int* in_sizes, int n_in,
                              void* d_out, int out_size, void* d_ws, size_t ws_size,
                              hipStream_t stream) {
  const float* clip = (const float*)d_in[0];
  const float* fr   = (const float*)d_in[1];
  const float* gn   = (const float*)d_in[2];
  const float* qs   = (const float*)d_in[3];
  float* out = (float*)d_out;
  float* eoT = (float*)d_ws;
  float* sgD = eoT + (size_t)NB * NCROW * 8;

  eq_a<<<NTILE, 64, 0, stream>>>(clip, fr, gn, qs, eoT);
  eq_b<<<NB, 64, 0, stream>>>(fr, gn, qs, eoT, sgD);
  eq_c<<<NTILE, 64, 0, stream>>>(clip, fr, gn, qs, sgD, out);
}

// Round 6
// 90.611 us; speedup vs baseline: 3.0017x; 1.0426x over previous
//
#include <hip/hip_runtime.h>
#include <math.h>

#define SRATE 32000.f
#define NB 128            // batch rows
#define NT 160000         // samples per row
#define CL 50             // samples per chunk
#define CPB 128           // chunks per block (1 per thread, 2 waves)
#define NCROW 3200        // chunks per row
#define NTILE 3200        // blocks for eq_a/eq_c (NB*NCROW/CPB)
#define TPR 25            // tiles per row (NCROW/CPB)
#define SEG 50            // chunks per lane in eq_b scan (NCROW/64)
#define LROW 52           // LDS row stride (floats)
#define RECROW (NCROW*8)  // floats per row in eoT/sgD

#ifndef M_PI
#define M_PI 3.14159265358979323846
#endif

// f32 coefficients, reference formula (hardware transcendentals).
__device__ __forceinline__ void coeffs_f32(
    const float* fr, const float* gn, const float* qs, float* c)
{
  #pragma unroll
  for (int f = 0; f < 3; ++f) {
    float w0 = 2.f * (float)M_PI * fr[f] / SRATE;
    float A  = expf(gn[f] * (2.302585093f / 40.f));   // 10^(g/40)
    float al = sinf(w0) / (2.f * qs[f]);
    float cw = cosf(w0);
    float a0 = 1.f + al / A;
    c[f*5+0] = (1.f + al*A) / a0;
    c[f*5+1] = -2.f * cw / a0;
    c[f*5+2] = (1.f - al*A) / a0;
    c[f*5+3] = -2.f * cw / a0;
    c[f*5+4] = (1.f - al/A) / a0;
  }
}

// LDS tile: 128 chunks x 52-float rows (26.6 KiB -> 6 blocks/CU = 12 waves/CU).
// (chunk s, sample-pair p) at lds[s*52 + ((p+s)%25)*2 + {0,1}] — rotation
// spreads banks; float2 ops keep 8B alignment.

// ---------------------------------------------------------------------------
// A: zero-entry-state cascade per chunk -> exit record (8 floats) in
// TRANSPOSED layout eoT[row][plane=c%SEG][slot=c/SEG] (eq_b reads coalesced).
// ---------------------------------------------------------------------------
__global__ __launch_bounds__(128) void eq_a(
    const float* __restrict__ x, const float* __restrict__ fr,
    const float* __restrict__ gn, const float* __restrict__ qs,
    float* __restrict__ eoT)
{
  __shared__ float lds[CPB * LROW];
  const int tid = threadIdx.x;
  const int t = blockIdx.x;
  float c[15];
  coeffs_f32(fr, gn, qs, c);
  const float* xg = x + (size_t)t * (CPB * CL);
  #pragma unroll
  for (int it = 0; it < 25; ++it) {            // 3200 float2 cooperative
    int f = it * 128 + tid;
    int seg = f / 25, off = f % 25;
    float2 v = *(const float2*)(xg + seg*CL + off*2);
    int pos = off + seg; pos -= (pos >= 25) ? 25 : 0; pos -= (pos >= 25) ? 25 : 0;
    pos = (off + seg) % 25;
    *(float2*)(&lds[seg*LROW + pos*2]) = v;
  }
  __syncthreads();
  const int gci = t * CPB + tid;
  const int ci  = gci % NCROW;                 // chunk index within row
  float x1, x2;
  if (tid == 0) {
    if (ci == 0) { x1 = 0.f; x2 = 0.f; }
    else { x1 = xg[-1]; x2 = xg[-2]; }
  } else {
    const int ps = tid - 1;
    const int pp = (ps + 24) % 25;
    x1 = lds[ps*LROW + pp*2 + 1];
    x2 = lds[ps*LROW + pp*2 + 0];
  }
  float y1p=0,y1pp=0,y2p=0,y2pp=0,y3p=0,y3pp=0;
  int rr = tid % 25;
  #pragma unroll
  for (int jj = 0; jj < 25; ++jj) {
    float2 xv = *(const float2*)(&lds[tid*LROW + rr*2]);
    rr = (rr == 24) ? 0 : rr + 1;
    #pragma unroll
    for (int q = 0; q < 2; ++q) {
      const float xn = q ? xv.y : xv.x;
      float y1 = c[0]*xn + c[1]*x1  + c[2]*x2   - c[3]*y1p  - c[4]*y1pp;
      float y2 = c[5]*y1 + c[6]*y1p + c[7]*y1pp - c[8]*y2p  - c[9]*y2pp;
      float y3 = c[10]*y2 + c[11]*y2p + c[12]*y2pp - c[13]*y3p - c[14]*y3pp;
      x2=x1; x1=xn;
      y1pp=y1p; y1p=y1; y2pp=y2p; y2p=y2; y3pp=y3p; y3p=y3;
    }
  }
  const int row = gci / NCROW;
  const int plane = ci % SEG, slot = ci / SEG;   // slot in [0,64)
  float* ep = eoT + (size_t)row * RECROW + ((size_t)plane*64 + slot)*8;
  float4 r0; r0.x=y1p; r0.y=y1pp; r0.z=y2p; r0.w=y2pp;
  float4 r1; r1.x=y3p; r1.y=y3pp; r1.z=0.f; r1.w=0.f;
  *(float4*)ep = r0; *(float4*)(ep+4) = r1;
}

// ---------------------------------------------------------------------------
// B: one 64-lane block per row. Prologue (f64): Hc = M^CL, G[k] = Hc^(SEG*2^k).
// 64-lane Kogge-Stone over 3200 chunk-exits; write TRUE entry states to
// sgD[row][chunk] (direct layout -> eq_c reads coalesced).
// ---------------------------------------------------------------------------
__global__ __launch_bounds__(64) void eq_b(
    const float* __restrict__ fr, const float* __restrict__ gn,
    const float* __restrict__ qs, const float* __restrict__ eoT,
    float* __restrict__ sgD)
{
  __shared__ double Mb[36], Rb[36], Tb[36];
  __shared__ float Hs[36], Gs[6*36];
  const int l = threadIdx.x, row = blockIdx.x;
  float c[15];
  coeffs_f32(fr, gn, qs, c);
  if (l < 6) {   // one-step homogeneous matrix M, column l
    double s0=0,s1=0,s2=0,s3=0,s4=0,s5=0;
    if (l==0) s0=1; else if (l==1) s1=1; else if (l==2) s2=1;
    else if (l==3) s3=1; else if (l==4) s4=1; else s5=1;
    double y1 = -(double)c[3]*s0 - (double)c[4]*s1;
    double y2 = (double)c[5]*y1 + (double)c[6]*s0 + (double)c[7]*s1
              - (double)c[8]*s2 - (double)c[9]*s3;
    double y3 = (double)c[10]*y2 + (double)c[11]*s2 + (double)c[12]*s3
              - (double)c[13]*s4 - (double)c[14]*s5;
    Mb[0*6+l]=y1; Mb[1*6+l]=s0; Mb[2*6+l]=y2; Mb[3*6+l]=s2; Mb[4*6+l]=y3; Mb[5*6+l]=s4;
  }
  if (l < 36) Rb[l] = ((l % 7) == 0) ? 1.0 : 0.0;
  __syncthreads();
  const int i = l / 6, j = l % 6;
  int e = CL;                                 // Rb = M^CL = Hc
  while (e) {
    if (e & 1) {
      double acc = 0.0;
      if (l < 36) { for (int k = 0; k < 6; ++k) acc += Rb[i*6+k]*Mb[k*6+j]; Tb[l]=acc; }
      __syncthreads();
      if (l < 36) Rb[l] = Tb[l];
      __syncthreads();
    }
    e >>= 1;
    if (e) {
      double acc = 0.0;
      if (l < 36) { for (int k = 0; k < 6; ++k) acc += Mb[i*6+k]*Mb[k*6+j]; Tb[l]=acc; }
      __syncthreads();
      if (l < 36) Mb[l] = Tb[l];
      __syncthreads();
    }
  }
  if (l < 36) { Hs[l] = (float)Rb[l]; Mb[l] = Rb[l]; }
  __syncthreads();
  if (l < 36) Rb[l] = ((l % 7) == 0) ? 1.0 : 0.0;
  __syncthreads();
  e = SEG;                                    // Rb = Hc^SEG
  while (e) {
    if (e & 1) {
      double acc = 0.0;
      if (l < 36) { for (int k = 0; k < 6; ++k) acc += Rb[i*6+k]*Mb[k*6+j]; Tb[l]=acc; }
      __syncthreads();
      if (l < 36) Rb[l] = Tb[l];
      __syncthreads();
    }
    e >>= 1;
    if (e) {
      double acc = 0.0;
      if (l < 36) { for (int k = 0; k < 6; ++k) acc += Mb[i*6+k]*Mb[k*6+j]; Tb[l]=acc; }
      __syncthreads();
      if (l < 36) Mb[l] = Tb[l];
      __syncthreads();
    }
  }
  if (l < 36) Gs[l] = (float)Rb[l];
  __syncthreads();
  for (int k = 1; k < 6; ++k) {               // Gs[k] = Gs[k-1]^2
    double acc = 0.0;
    if (l < 36) { for (int m = 0; m < 6; ++m) acc += Rb[i*6+m]*Rb[m*6+j]; Tb[l]=acc; }
    __syncthreads();
    if (l < 36) Rb[l] = Tb[l];
    __syncthreads();
    if (l < 36) Gs[k*36+l] = (float)Rb[l];
    __syncthreads();
  }

  float H[36];
  #pragma unroll
  for (int q = 0; q < 36; ++q) H[q] = Hs[q];
  const float* rbase = eoT + (size_t)row * RECROW;
  // local zero-entry scan over this lane's SEG chunks (coalesced plane reads)
  float u[6] = {0,0,0,0,0,0};
  for (int jj = 0; jj < SEG; ++jj) {
    const float* ep = rbase + ((size_t)jj*64 + l)*8;
    float4 r0 = *(const float4*)ep, r1 = *(const float4*)(ep+4);
    float ev[6] = {r0.x,r0.y,r0.z,r0.w,r1.x,r1.y};
    float nu[6];
    #pragma unroll
    for (int q = 0; q < 6; ++q) {
      float a = ev[q];
      #pragma unroll
      for (int m = 0; m < 6; ++m) a += H[q*6+m]*u[m];
      nu[q] = a;
    }
    #pragma unroll
    for (int q = 0; q < 6; ++q) u[q] = nu[q];
  }
  // Kogge-Stone inclusive scan across lanes
  float v6[6];
  #pragma unroll
  for (int q = 0; q < 6; ++q) v6[q] = u[q];
  #pragma unroll
  for (int k = 0; k < 6; ++k) {
    const float* G = Gs + k*36;
    float o[6];
    #pragma unroll
    for (int q = 0; q < 6; ++q) o[q] = __shfl_up(v6[q], 1u << k, 64);
    if (l >= (1 << k)) {
      float nv[6];
      #pragma unroll
      for (int q = 0; q < 6; ++q) {
        float a = v6[q];
        #pragma unroll
        for (int m = 0; m < 6; ++m) a += G[q*6+m]*o[m];
        nv[q] = a;
      }
      #pragma unroll
      for (int q = 0; q < 6; ++q) v6[q] = nv[q];
    }
  }
  float s[6];
  #pragma unroll
  for (int q = 0; q < 6; ++q) s[q] = __shfl_up(v6[q], 1, 64);
  if (l == 0) {
    #pragma unroll
    for (int q = 0; q < 6; ++q) s[q] = 0.f;
  }
  // replay: write true entry of chunk c = l*SEG + jj (direct layout)
  float* wbase = sgD + (size_t)row * RECROW;
  for (int jj = 0; jj < SEG; ++jj) {
    const float* ep = rbase + ((size_t)jj*64 + l)*8;
    float4 r0 = *(const float4*)ep, r1 = *(const float4*)(ep+4);
    float ev[6] = {r0.x,r0.y,r0.z,r0.w,r1.x,r1.y};
    float* wp = wbase + ((size_t)l*SEG + jj)*8;
    float4 w0; w0.x=s[0]; w0.y=s[1]; w0.z=s[2]; w0.w=s[3];
    float4 w1; w1.x=s[4]; w1.y=s[5]; w1.z=0.f; w1.w=0.f;
    *(float4*)wp = w0; *(float4*)(wp+4) = w1;
    float ns[6];
    #pragma unroll
    for (int q = 0; q < 6; ++q) {
      float a = ev[q];
      #pragma unroll
      for (int m = 0; m < 6; ++m) a += H[q*6+m]*s[m];
      ns[q] = a;
    }
    #pragma unroll
    for (int q = 0; q < 6; ++q) s[q] = ns[q];
  }
}

// ---------------------------------------------------------------------------
// C: exact cascade per chunk with true entry state (coalesced sgD read);
// writes final output through LDS (coalesced).
// ---------------------------------------------------------------------------
__global__ __launch_bounds__(128) void eq_c(
    const float* __restrict__ x, const float* __restrict__ fr,
    const float* __restrict__ gn, const float* __restrict__ qs,
    const float* __restrict__ sgD, float* __restrict__ y)
{
  __shared__ float lds[CPB * LROW];
  const int tid = threadIdx.x;
  const int t = blockIdx.x;
  float c[15];
  coeffs_f32(fr, gn, qs, c);
  const float* xg = x + (size_t)t * (CPB * CL);
  float* yg = y + (size_t)t * (CPB * CL);
  #pragma unroll
  for (int it = 0; it < 25; ++it) {
    int f = it * 128 + tid;
    int seg = f / 25, off = f % 25;
    float2 v = *(const float2*)(xg + seg*CL + off*2);
    int pos = (off + seg) % 25;
    *(float2*)(&lds[seg*LROW + pos*2]) = v;
  }
  __syncthreads();
  const int gci = t * CPB + tid;
  const int ci  = gci % NCROW;
  float x1, x2;
  if (tid == 0) {
    if (ci == 0) { x1 = 0.f; x2 = 0.f; }
    else { x1 = xg[-1]; x2 = xg[-2]; }
  } else {
    const int ps = tid - 1;
    const int pp = (ps + 24) % 25;
    x1 = lds[ps*LROW + pp*2 + 1];
    x2 = lds[ps*LROW + pp*2 + 0];
  }
  __syncthreads();   // cross-wave history reads complete before overwrite
  const int row = gci / NCROW;
  const float* sp = sgD + (size_t)row * RECROW + (size_t)ci * 8;
  float4 s0 = *(const float4*)sp, s1 = *(const float4*)(sp+4);
  float y1p=s0.x, y1pp=s0.y, y2p=s0.z, y2pp=s0.w, y3p=s1.x, y3pp=s1.y;
  int rr = tid % 25;
  #pragma unroll
  for (int jj = 0; jj < 25; ++jj) {
    float2 xv = *(const float2*)(&lds[tid*LROW + rr*2]);
    float2 yv;
    #pragma unroll
    for (int q = 0; q < 2; ++q) {
      const float xn = q ? xv.y : xv.x;
      float y1 = c[0]*xn + c[1]*x1  + c[2]*x2   - c[3]*y1p  - c[4]*y1pp;
      float y2 = c[5]*y1 + c[6]*y1p + c[7]*y1pp - c[8]*y2p  - c[9]*y2pp;
      float y3 = c[10]*y2 + c[11]*y2p + c[12]*y2pp - c[13]*y3p - c[14]*y3pp;
      x2=x1; x1=xn;
      y1pp=y1p; y1p=y1; y2pp=y2p; y2p=y2; y3pp=y3p; y3p=y3;
      if (q) yv.y = y3; else yv.x = y3;
    }
    *(float2*)(&lds[tid*LROW + rr*2]) = yv;   // own row only
    rr = (rr == 24) ? 0 : rr + 1;
  }
  __syncthreads();
  #pragma unroll
  for (int it = 0; it < 25; ++it) {
    int f = it * 128 + tid;
    int seg = f / 25, off = f % 25;
    int pos = (off + seg) % 25;
    float2 v = *(const float2*)(&lds[seg*LROW + pos*2]);
    *(float2*)(yg + seg*CL + off*2) = v;
  }
}

// ws: eoT [0, 13.1MB) | sgD [13.1MB, 26.2MB)  (8-float records)
extern "C" void kernel_launch(void* const* d_in, const int* in_sizes, int n_in,
                              void* d_out, int out_size, void* d_ws, size_t ws_size,
                              hipStream_t stream) {
  const float* clip = (const float*)d_in[0];
  const float* fr   = (const float*)d_in[1];
  const float* gn   = (const float*)d_in[2];
  const float* qs   = (const float*)d_in[3];
  float* out = (float*)d_out;
  float* eoT = (float*)d_ws;
  float* sgD = eoT + (size_t)NB * RECROW;

  eq_a<<<NTILE, 128, 0, stream>>>(clip, fr, gn, qs, eoT);
  eq_b<<<NB, 64, 0, stream>>>(fr, gn, qs, eoT, sgD);
  eq_c<<<NTILE, 128, 0, stream>>>(clip, fr, gn, qs, sgD, out);
}

// Round 7
// 76.545 us; speedup vs baseline: 3.5532x; 1.1838x over previous
//
#include <hip/hip_runtime.h>
#include <math.h>

#define SRATE 32000.f
#define NB 128            // batch rows
#define NT 160000         // samples per row
#define CL 50             // samples per chunk
#define CPB 128           // chunks per tile (1 per thread, 2 waves)
#define NCROW 3200        // chunks per row
#define NTILE 3200        // tiles total
#define TPR 25            // tiles per row
#define SEG 50            // chunks per lane in eq_b scan (NCROW/64)
#define TILEF 6400        // floats per tile (CPB*CL)
#define GRID 768          // persistent blocks (3/CU resident, 51.2KB LDS)
#define RECROW (NCROW*8)  // floats per row in eoT/sgD

#ifndef M_PI
#define M_PI 3.14159265358979323846
#endif

// f32 coefficients, reference formula (hardware transcendentals).
__device__ __forceinline__ void coeffs_f32(
    const float* fr, const float* gn, const float* qs, float* c)
{
  #pragma unroll
  for (int f = 0; f < 3; ++f) {
    float w0 = 2.f * (float)M_PI * fr[f] / SRATE;
    float A  = expf(gn[f] * (2.302585093f / 40.f));   // 10^(g/40)
    float al = sinf(w0) / (2.f * qs[f]);
    float cw = cosf(w0);
    float a0 = 1.f + al / A;
    c[f*5+0] = (1.f + al*A) / a0;
    c[f*5+1] = -2.f * cw / a0;
    c[f*5+2] = (1.f - al*A) / a0;
    c[f*5+3] = -2.f * cw / a0;
    c[f*5+4] = (1.f - al/A) / a0;
  }
}

// Async stage of one wave's half-tile (3200 floats) via global_load_lds:
// 12 full 1KB calls + 1 half call (lanes 0-31). Linear LDS dest (HW adds
// lane*16B to the uniform base). src0/dst0 exclude the lane term.
__device__ __forceinline__ void stage_half(
    const float* __restrict__ src0, float* dst0, int lane)
{
  const float* src = src0 + lane * 4;
  #pragma unroll
  for (int cc = 0; cc < 12; ++cc) {
    __builtin_amdgcn_global_load_lds(
        (const __attribute__((address_space(1))) void*)(src + cc*256),
        (__attribute__((address_space(3))) void*)(dst0 + cc*256), 16, 0, 0);
  }
  if (lane < 32) {
    __builtin_amdgcn_global_load_lds(
        (const __attribute__((address_space(1))) void*)(src + 12*256),
        (__attribute__((address_space(3))) void*)(dst0 + 12*256), 16, 0, 0);
  }
}

// ---------------------------------------------------------------------------
// A: persistent 2-phase pipeline. Per tile: stage(next) || compute(cur).
// Zero-entry-state cascade per chunk -> exit record (8 floats) in TRANSPOSED
// layout eoT[row][plane=ci%SEG][slot=ci/SEG] (eq_b reads coalesced).
// LDS rows are LINEAR (stride 50): float2 reads sit at the 4-word/bank floor.
// ---------------------------------------------------------------------------
__global__ __launch_bounds__(128) void eq_a(
    const float* __restrict__ x, const float* __restrict__ fr,
    const float* __restrict__ gn, const float* __restrict__ qs,
    float* __restrict__ eoT)
{
  __shared__ float lds[2][TILEF];
  const int tid = threadIdx.x, lane = tid & 63, wave = tid >> 6;
  float c[15];
  coeffs_f32(fr, gn, qs, c);
  const int b = blockIdx.x;
  stage_half(x + (size_t)b*TILEF + wave*3200, &lds[0][wave*3200], lane);
  __syncthreads();                       // implicit vmcnt(0): tile 0 ready
  int cur = 0;
  for (int t = b; t < NTILE; t += GRID) {
    const int tn = t + GRID;
    if (tn < NTILE)
      stage_half(x + (size_t)tn*TILEF + wave*3200, &lds[cur^1][wave*3200], lane);
    const int gch = t*CPB + tid;
    const int ci  = (t % TPR)*CPB + tid;
    float bx1 = 0.f, bx2 = 0.f;
    if (lane == 0 && ci != 0) {          // cross-tile boundary from global
      const float* p = x + (size_t)gch * CL;
      bx1 = p[-1]; bx2 = p[-2];
    }
    const float* myrow = &lds[cur][tid*CL];
    float a48 = myrow[48], a49 = myrow[49];
    float x1 = __shfl_up(a49, 1, 64), x2 = __shfl_up(a48, 1, 64);
    if (lane == 0) { x1 = bx1; x2 = bx2; }
    float y1p=0,y1pp=0,y2p=0,y2pp=0,y3p=0,y3pp=0;
    #pragma unroll
    for (int j = 0; j < 25; ++j) {
      float2 xv = *(const float2*)(myrow + 2*j);
      #pragma unroll
      for (int q = 0; q < 2; ++q) {
        const float xn = q ? xv.y : xv.x;
        float y1 = c[0]*xn + c[1]*x1  + c[2]*x2   - c[3]*y1p  - c[4]*y1pp;
        float y2 = c[5]*y1 + c[6]*y1p + c[7]*y1pp - c[8]*y2p  - c[9]*y2pp;
        float y3 = c[10]*y2 + c[11]*y2p + c[12]*y2pp - c[13]*y3p - c[14]*y3pp;
        x2=x1; x1=xn;
        y1pp=y1p; y1p=y1; y2pp=y2p; y2p=y2; y3pp=y3p; y3p=y3;
      }
    }
    const int row = t / TPR;
    const int plane = ci % SEG, slot = ci / SEG;
    float* ep = eoT + (size_t)row * RECROW + ((size_t)(plane*64 + slot))*8;
    float4 r0; r0.x=y1p; r0.y=y1pp; r0.z=y2p; r0.w=y2pp;
    float4 r1; r1.x=y3p; r1.y=y3pp; r1.z=0.f; r1.w=0.f;
    *(float4*)ep = r0; *(float4*)(ep+4) = r1;
    __syncthreads();                     // next tile staged; cur free to swap
    cur ^= 1;
  }
}

// ---------------------------------------------------------------------------
// B: one 64-lane block per row. Prologue (f64): Hc = M^CL, G[k] = Hc^(SEG*2^k).
// 64-lane Kogge-Stone over 3200 chunk-exits; write TRUE entry states to
// sgD[row][chunk] (direct layout -> eq_c reads coalesced). (verified r6)
// ---------------------------------------------------------------------------
__global__ __launch_bounds__(64) void eq_b(
    const float* __restrict__ fr, const float* __restrict__ gn,
    const float* __restrict__ qs, const float* __restrict__ eoT,
    float* __restrict__ sgD)
{
  __shared__ double Mb[36], Rb[36], Tb[36];
  __shared__ float Hs[36], Gs[6*36];
  const int l = threadIdx.x, row = blockIdx.x;
  float c[15];
  coeffs_f32(fr, gn, qs, c);
  if (l < 6) {   // one-step homogeneous matrix M, column l
    double s0=0,s1=0,s2=0,s3=0,s4=0,s5=0;
    if (l==0) s0=1; else if (l==1) s1=1; else if (l==2) s2=1;
    else if (l==3) s3=1; else if (l==4) s4=1; else s5=1;
    double y1 = -(double)c[3]*s0 - (double)c[4]*s1;
    double y2 = (double)c[5]*y1 + (double)c[6]*s0 + (double)c[7]*s1
              - (double)c[8]*s2 - (double)c[9]*s3;
    double y3 = (double)c[10]*y2 + (double)c[11]*s2 + (double)c[12]*s3
              - (double)c[13]*s4 - (double)c[14]*s5;
    Mb[0*6+l]=y1; Mb[1*6+l]=s0; Mb[2*6+l]=y2; Mb[3*6+l]=s2; Mb[4*6+l]=y3; Mb[5*6+l]=s4;
  }
  if (l < 36) Rb[l] = ((l % 7) == 0) ? 1.0 : 0.0;
  __syncthreads();
  const int i = l / 6, j = l % 6;
  int e = CL;                                 // Rb = M^CL = Hc
  while (e) {
    if (e & 1) {
      double acc = 0.0;
      if (l < 36) { for (int k = 0; k < 6; ++k) acc += Rb[i*6+k]*Mb[k*6+j]; Tb[l]=acc; }
      __syncthreads();
      if (l < 36) Rb[l] = Tb[l];
      __syncthreads();
    }
    e >>= 1;
    if (e) {
      double acc = 0.0;
      if (l < 36) { for (int k = 0; k < 6; ++k) acc += Mb[i*6+k]*Mb[k*6+j]; Tb[l]=acc; }
      __syncthreads();
      if (l < 36) Mb[l] = Tb[l];
      __syncthreads();
    }
  }
  if (l < 36) { Hs[l] = (float)Rb[l]; Mb[l] = Rb[l]; }
  __syncthreads();
  if (l < 36) Rb[l] = ((l % 7) == 0) ? 1.0 : 0.0;
  __syncthreads();
  e = SEG;                                    // Rb = Hc^SEG
  while (e) {
    if (e & 1) {
      double acc = 0.0;
      if (l < 36) { for (int k = 0; k < 6; ++k) acc += Rb[i*6+k]*Mb[k*6+j]; Tb[l]=acc; }
      __syncthreads();
      if (l < 36) Rb[l] = Tb[l];
      __syncthreads();
    }
    e >>= 1;
    if (e) {
      double acc = 0.0;
      if (l < 36) { for (int k = 0; k < 6; ++k) acc += Mb[i*6+k]*Mb[k*6+j]; Tb[l]=acc; }
      __syncthreads();
      if (l < 36) Mb[l] = Tb[l];
      __syncthreads();
    }
  }
  if (l < 36) Gs[l] = (float)Rb[l];
  __syncthreads();
  for (int k = 1; k < 6; ++k) {               // Gs[k] = Gs[k-1]^2
    double acc = 0.0;
    if (l < 36) { for (int m = 0; m < 6; ++m) acc += Rb[i*6+m]*Rb[m*6+j]; Tb[l]=acc; }
    __syncthreads();
    if (l < 36) Rb[l] = Tb[l];
    __syncthreads();
    if (l < 36) Gs[k*36+l] = (float)Rb[l];
    __syncthreads();
  }

  float H[36];
  #pragma unroll
  for (int q = 0; q < 36; ++q) H[q] = Hs[q];
  const float* rbase = eoT + (size_t)row * RECROW;
  float u[6] = {0,0,0,0,0,0};
  for (int jj = 0; jj < SEG; ++jj) {          // local zero-entry scan
    const float* ep = rbase + ((size_t)jj*64 + l)*8;
    float4 r0 = *(const float4*)ep, r1 = *(const float4*)(ep+4);
    float ev[6] = {r0.x,r0.y,r0.z,r0.w,r1.x,r1.y};
    float nu[6];
    #pragma unroll
    for (int q = 0; q < 6; ++q) {
      float a = ev[q];
      #pragma unroll
      for (int m = 0; m < 6; ++m) a += H[q*6+m]*u[m];
      nu[q] = a;
    }
    #pragma unroll
    for (int q = 0; q < 6; ++q) u[q] = nu[q];
  }
  float v6[6];
  #pragma unroll
  for (int q = 0; q < 6; ++q) v6[q] = u[q];
  #pragma unroll
  for (int k = 0; k < 6; ++k) {               // Kogge-Stone
    const float* G = Gs + k*36;
    float o[6];
    #pragma unroll
    for (int q = 0; q < 6; ++q) o[q] = __shfl_up(v6[q], 1u << k, 64);
    if (l >= (1 << k)) {
      float nv[6];
      #pragma unroll
      for (int q = 0; q < 6; ++q) {
        float a = v6[q];
        #pragma unroll
        for (int m = 0; m < 6; ++m) a += G[q*6+m]*o[m];
        nv[q] = a;
      }
      #pragma unroll
      for (int q = 0; q < 6; ++q) v6[q] = nv[q];
    }
  }
  float s[6];
  #pragma unroll
  for (int q = 0; q < 6; ++q) s[q] = __shfl_up(v6[q], 1, 64);
  if (l == 0) {
    #pragma unroll
    for (int q = 0; q < 6; ++q) s[q] = 0.f;
  }
  float* wbase = sgD + (size_t)row * RECROW;
  for (int jj = 0; jj < SEG; ++jj) {          // replay: true entries
    const float* ep = rbase + ((size_t)jj*64 + l)*8;
    float4 r0 = *(const float4*)ep, r1 = *(const float4*)(ep+4);
    float ev[6] = {r0.x,r0.y,r0.z,r0.w,r1.x,r1.y};
    float* wp = wbase + ((size_t)l*SEG + jj)*8;
    float4 w0; w0.x=s[0]; w0.y=s[1]; w0.z=s[2]; w0.w=s[3];
    float4 w1; w1.x=s[4]; w1.y=s[5]; w1.z=0.f; w1.w=0.f;
    *(float4*)wp = w0; *(float4*)(wp+4) = w1;
    float ns[6];
    #pragma unroll
    for (int q = 0; q < 6; ++q) {
      float a = ev[q];
      #pragma unroll
      for (int m = 0; m < 6; ++m) a += H[q*6+m]*s[m];
      ns[q] = a;
    }
    #pragma unroll
    for (int q = 0; q < 6; ++q) s[q] = ns[q];
  }
}

// ---------------------------------------------------------------------------
// C: persistent 2-phase pipeline. Per tile: stage(next) || compute(cur) with
// true entry state (coalesced sgD read); y written back in place in LDS then
// cooperatively stored (coalesced). Two barriers per tile (WAR on y-store).
// ---------------------------------------------------------------------------
__global__ __launch_bounds__(128) void eq_c(
    const float* __restrict__ x, const float* __restrict__ fr,
    const float* __restrict__ gn, const float* __restrict__ qs,
    const float* __restrict__ sgD, float* __restrict__ y)
{
  __shared__ float lds[2][TILEF];
  const int tid = threadIdx.x, lane = tid & 63, wave = tid >> 6;
  float c[15];
  coeffs_f32(fr, gn, qs, c);
  const int b = blockIdx.x;
  stage_half(x + (size_t)b*TILEF + wave*3200, &lds[0][wave*3200], lane);
  __syncthreads();
  int cur = 0;
  for (int t = b; t < NTILE; t += GRID) {
    const int tn = t + GRID;
    if (tn < NTILE)
      stage_half(x + (size_t)tn*TILEF + wave*3200, &lds[cur^1][wave*3200], lane);
    const int gch = t*CPB + tid;
    const int ci  = (t % TPR)*CPB + tid;
    const int row = t / TPR;
    float bx1 = 0.f, bx2 = 0.f;
    if (lane == 0 && ci != 0) {
      const float* p = x + (size_t)gch * CL;
      bx1 = p[-1]; bx2 = p[-2];
    }
    const float* sp = sgD + (size_t)row * RECROW + (size_t)ci * 8;
    float4 s0 = *(const float4*)sp, s1 = *(const float4*)(sp+4);
    float* myrow = &lds[cur][tid*CL];
    float a48 = myrow[48], a49 = myrow[49];
    float x1 = __shfl_up(a49, 1, 64), x2 = __shfl_up(a48, 1, 64);
    if (lane == 0) { x1 = bx1; x2 = bx2; }
    float y1p=s0.x, y1pp=s0.y, y2p=s0.z, y2pp=s0.w, y3p=s1.x, y3pp=s1.y;
    #pragma unroll
    for (int j = 0; j < 25; ++j) {
      float2 xv = *(const float2*)(myrow + 2*j);
      float2 yv;
      #pragma unroll
      for (int q = 0; q < 2; ++q) {
        const float xn = q ? xv.y : xv.x;
        float y1 = c[0]*xn + c[1]*x1  + c[2]*x2   - c[3]*y1p  - c[4]*y1pp;
        float y2 = c[5]*y1 + c[6]*y1p + c[7]*y1pp - c[8]*y2p  - c[9]*y2pp;
        float y3 = c[10]*y2 + c[11]*y2p + c[12]*y2pp - c[13]*y3p - c[14]*y3pp;
        x2=x1; x1=xn;
        y1pp=y1p; y1p=y1; y2pp=y2p; y2p=y2; y3pp=y3p; y3p=y3;
        if (q) yv.y = y3; else yv.x = y3;
      }
      *(float2*)(myrow + 2*j) = yv;     // overwrite own row with y
    }
    __syncthreads();                    // stage(next) done + y-writes visible
    float* yg = y + (size_t)t * TILEF;
    #pragma unroll
    for (int it = 0; it < 25; ++it) {   // coalesced y store
      int f = it * 128 + tid;
      float2 v = *(const float2*)(&lds[cur][2*f]);
      *(float2*)(yg + 2*f) = v;
    }
    __syncthreads();                    // y-store reads done (WAR vs next stage)
    cur ^= 1;
  }
}

// ws: eoT [0, 13.1MB) | sgD [13.1MB, 26.2MB)  (8-float records)
extern "C" void kernel_launch(void* const* d_in, const int* in_sizes, int n_in,
                              void* d_out, int out_size, void* d_ws, size_t ws_size,
                              hipStream_t stream) {
  const float* clip = (const float*)d_in[0];
  const float* fr   = (const float*)d_in[1];
  const float* gn   = (const float*)d_in[2];
  const float* qs   = (const float*)d_in[3];
  float* out = (float*)d_out;
  float* eoT = (float*)d_ws;
  float* sgD = eoT + (size_t)NB * RECROW;

  eq_a<<<GRID, 128, 0, stream>>>(clip, fr, gn, qs, eoT);
  eq_b<<<NB, 64, 0, stream>>>(fr, gn, qs, eoT, sgD);
  eq_c<<<GRID, 128, 0, stream>>>(clip, fr, gn, qs, sgD, out);
}